// Round 11
// baseline (921.683 us; speedup 1.0000x reference)
//
#include <hip/hip_runtime.h>

#define CIN    256
#define WID    48
#define HWD    2304            // 48*48
#define PHW    2500            // 50*50 padded
#define NTB    64              // ts(16) * b(4)
#define SLICE  (4*CIN*HWD)

// ws (bytes): Xtp half [32tb][4 g][2500 pp][64ci] bf16 = 40,960,000
//             At [2by][36 kt2][8192 shorts]           =  1,179,648
//             Y bf16                                   = 75,497,472 (ends 117,637,120)
#define WS_XT  0
#define WS_AT  40960000
#define WS_Y   42139648

typedef __attribute__((ext_vector_type(8))) short short8v;  // 8 bf16
typedef __attribute__((ext_vector_type(4))) float f32x4;

__device__ __forceinline__ unsigned short f2bf(float f) {
    unsigned u = __float_as_uint(f);
    u = (u + 0x7fffu + ((u >> 16) & 1u)) >> 16;   // RNE
    return (unsigned short)u;
}
__device__ __forceinline__ float bf2f(unsigned short s) {
    return __uint_as_float(((unsigned)s) << 16);
}
__device__ __forceinline__ void gload_lds16(const void* g, void* l) {
    __builtin_amdgcn_global_load_lds(
        (const __attribute__((address_space(1))) unsigned int*)g,
        (__attribute__((address_space(3))) unsigned int*)l, 16, 0, 0);
}

// ---- prep_w (round-6 exact): W fp32 -> At bf16, pre-swizzled LDS image, kt2 = g*9+tap
__global__ __launch_bounds__(256) void prep_w_k(const float* __restrict__ Wt,
                                                unsigned short* __restrict__ At)
{
    const int s = (blockIdx.x * 256 + threadIdx.x) * 8;   // short index < 589824
    const int tile = s >> 13;                 // by*36 + kt2
    const int row  = (s & 8191) >> 6;
    const int colb = (s & 63) * 2;            // byte col (16B-aligned)
    const int by = tile / 36, kt2 = tile - by * 36;
    const int g = kt2 / 9, tap = kt2 - g * 9;
    const int k0 = (colb ^ ((row & 7) << 4)) >> 1;   // elem 0..63, 8-aligned
    const int co = by * 128 + row;
    const float* wp = Wt + (size_t)co * 2304 + (g * 64 + k0) * 9 + tap;
    short8v v;
    #pragma unroll
    for (int j = 0; j < 8; ++j) v[j] = (short)f2bf(wp[j * 9]);
    *(short8v*)(At + s) = v;
}

// ---- prep_x (round-6 exact): X fp32 [32tb][ci][px] -> Xtp bf16 [32tb][g][pp][64ci]
__global__ __launch_bounds__(256) void prep_x_k(const float* __restrict__ X,
                                                unsigned short* __restrict__ Xtp)
{
    __shared__ unsigned short t_[64][72];
    const int tid = threadIdx.x;
    const int px0 = blockIdx.x * 64;
    const int g   = blockIdx.y;               // ci group of 64
    const int tb  = blockIdx.z;

    const int ci_l = tid >> 2, pg = (tid & 3) * 16;
    const float* xp = X + ((size_t)tb * CIN + g * 64 + ci_l) * HWD + px0 + pg;
    #pragma unroll
    for (int q = 0; q < 4; ++q) {
        f32x4 v = *(const f32x4*)(xp + q * 4);
        #pragma unroll
        for (int e = 0; e < 4; ++e)
            t_[pg + q * 4 + e][ci_l] = f2bf(v[e]);
    }
    __syncthreads();
    const int px_l = tid >> 2, cg = (tid & 3) * 16;
    const int p  = px0 + px_l;
    const int pp = p + (p / WID) * 2 + 51;    // (h+1)*50 + (w+1)
    unsigned short* op = Xtp + (((size_t)tb * 4 + g) * PHW + pp) * 64 + cg;
    *(short8v*)op       = *(const short8v*)&t_[px_l][cg];
    *(short8v*)(op + 8) = *(const short8v*)&t_[px_l][cg + 8];
}

// ---- conv: round-6 structure + T14 async A-stage (global->reg 2-deep, reg->LDS write)
__global__ __launch_bounds__(256, 2) void conv12_k(
    const unsigned short* __restrict__ Xtp, const unsigned short* __restrict__ At,
    const float* __restrict__ Bs, unsigned short* __restrict__ Y, int tb_base)
{
    __shared__ short ldsA[2][8192];    // 2 x 16 KB
    __shared__ short ldsB[19200];      // slab: 300 cells x 128B (37.5 KB)

    const int tid = threadIdx.x;
    const int wv  = tid >> 6, ln = tid & 63;
    const int lr  = ln & 15,  lg = ln >> 4;
    const int wm  = wv >> 1,  wn = wv & 1;

    // bijective XCD swizzle, nwg=768 (q=96); by-pairs adjacent
    const int orig = blockIdx.x;
    const int wg   = (orig & 7) * 96 + (orig >> 3);
    const int by   = wg & 1;
    const int pair = wg >> 1;            // 0..383
    const int tb_l = pair / 12;
    const int rt   = pair - tb_l * 12;   // 0..11 (4 image rows)

    int boff[6];
    #pragma unroll
    for (int ni = 0; ni < 6; ++ni) {
        const int p = wn * 96 + ni * 16 + lr;
        const int r = p / 48, c = p - r * 48;
        boff[ni] = (r + 1) * 50 + (c + 1);
    }
    const int cx0 = ((lg << 4) ^ ((lr & 7) << 4)) >> 1;
    const int cx1 = ((64 | (lg << 4)) ^ ((lr & 7) << 4)) >> 1;

    const unsigned short* Asrc  = At + (size_t)by * 36 * 8192 + wv * 2048 + ln * 8;
    const unsigned short* slab0 = Xtp + (size_t)tb_l * 4 * PHW * 64 + (size_t)rt * 200 * 64;

    f32x4 acc[4][6];
    const f32x4 zero = {0.f, 0.f, 0.f, 0.f};
    #pragma unroll
    for (int i = 0; i < 4; ++i)
        #pragma unroll
        for (int j = 0; j < 6; ++j) acc[i][j] = zero;

    short8v rA0[4], rA1[4];             // 2-deep A reg staging (named: rule #20)

    auto issueA = [&](int kt2, int slot) {     // global -> regs (flat 16B loads)
        const unsigned short* ap = Asrc + (size_t)kt2 * 8192;
        if (slot == 0) {
            #pragma unroll
            for (int i = 0; i < 4; ++i) rA0[i] = *(const short8v*)(ap + i * 512);
        } else {
            #pragma unroll
            for (int i = 0; i < 4; ++i) rA1[i] = *(const short8v*)(ap + i * 512);
        }
    };
    auto writeA = [&](int j) {                 // regs(slot j&1) -> ldsA[j&1]
        if ((j & 1) == 0) {
            #pragma unroll
            for (int i = 0; i < 4; ++i)
                *(short8v*)&ldsA[0][wv * 2048 + i * 512 + ln * 8] = rA0[i];
        } else {
            #pragma unroll
            for (int i = 0; i < 4; ++i)
                *(short8v*)&ldsA[1][wv * 2048 + i * 512 + ln * 8] = rA1[i];
        }
    };
    auto stage_slab = [&](int g) {             // round-6 exact (gload_lds)
        const unsigned short* sg = slab0 + (size_t)g * PHW * 64;
        #pragma unroll
        for (int j = 0; j < 10; ++j) {
            const int cc = tid + 256 * j;
            if (cc < 2400) {
                const int p = cc >> 3, k = cc & 7;
                gload_lds16(sg + p * 64 + ((k ^ (p & 7)) << 3),
                            &ldsB[(wv * 64 + 256 * j) * 8]);
            }
        }
    };

    // prologue
    issueA(0, 0);
    issueA(1, 1);
    stage_slab(0);
    __syncthreads();                          // full drain once (prologue only)
    writeA(0);
    asm volatile("s_waitcnt lgkmcnt(0)" ::: "memory");
    __builtin_amdgcn_sched_barrier(0);
    __builtin_amdgcn_s_barrier();
    __builtin_amdgcn_sched_barrier(0);

    for (int g = 0; g < 4; ++g) {
        #pragma unroll
        for (int tap = 0; tap < 9; ++tap) {
            const int kt2 = g * 9 + tap;
            if (kt2 + 2 <= 35) issueA(kt2 + 2, kt2 & 1);   // 2-deep prefetch
            __builtin_amdgcn_sched_barrier(0);             // pin loads above MFMA

            const int cur  = kt2 & 1;
            const int toff = (tap / 3 - 1) * 50 + (tap % 3) - 1;
            #pragma unroll
            for (int kh = 0; kh < 2; ++kh) {
                const int cx = kh ? cx1 : cx0;
                short8v a_[4], b_[6];
                #pragma unroll
                for (int mi = 0; mi < 4; ++mi)
                    a_[mi] = *(const short8v*)&ldsA[cur][(wm * 64 + mi * 16 + lr) * 64 + cx];
                #pragma unroll
                for (int ni = 0; ni < 6; ++ni) {
                    const int sp = boff[ni] + toff;
                    b_[ni] = *(const short8v*)&ldsB[sp * 64 + ((((kh << 2) | lg) ^ (sp & 7)) << 3)];
                }
                __builtin_amdgcn_s_setprio(1);
                #pragma unroll
                for (int mi = 0; mi < 4; ++mi)
                    #pragma unroll
                    for (int ni = 0; ni < 6; ++ni)
                        acc[mi][ni] = __builtin_amdgcn_mfma_f32_16x16x32_bf16(
                            a_[mi], b_[ni], acc[mi][ni], 0, 0, 0);
                __builtin_amdgcn_s_setprio(0);
            }

            if (tap < 8 || g < 3) {            // write A(kt2+1) into buf (kt2+1)&1
                writeA(kt2 + 1);               // compiler inserts exact vmcnt wait
                asm volatile("s_waitcnt lgkmcnt(0)" ::: "memory");
                __builtin_amdgcn_sched_barrier(0);
                __builtin_amdgcn_s_barrier();
                __builtin_amdgcn_sched_barrier(0);
            }
            if (tap == 8 && g < 3) {           // slab for next ci-group
                stage_slab(g + 1);
                asm volatile("s_waitcnt vmcnt(0)" ::: "memory");
                __builtin_amdgcn_sched_barrier(0);
                __builtin_amdgcn_s_barrier();
                __builtin_amdgcn_sched_barrier(0);
            }
        }
    }

    // epilogue (round-6 exact): D row=(lane>>4)*4+r (m), col=lane&15 (px)
    const int tbg   = tb_base + tb_l;
    const int nbase = rt * 192 + wn * 96;
    #pragma unroll
    for (int mi = 0; mi < 4; ++mi) {
        const int m = by * 128 + wm * 64 + mi * 16 + lg * 4;
        const f32x4 b4 = *(const f32x4*)&Bs[m];
        #pragma unroll
        for (int r = 0; r < 4; ++r) {
            unsigned short* yp = Y + ((size_t)tbg * CIN + m + r) * HWD + nbase;
            #pragma unroll
            for (int ni = 0; ni < 6; ++ni)
                yp[ni * 16 + lr] = f2bf(acc[mi][ni][r] + b4[r]);
        }
    }
}

// ---- LI scan in place on bf16 Y, 4 elems/thread
__global__ __launch_bounds__(256) void li_scan_k(uint2* __restrict__ Y)
{
    const int n = blockIdx.x * 256 + threadIdx.x;
    float v[4] = {0.f, 0.f, 0.f, 0.f}, c[4] = {0.f, 0.f, 0.f, 0.f};
    #pragma unroll
    for (int t = 0; t < 16; ++t) {
        const size_t idx = (size_t)t * (SLICE / 4) + n;
        uint2 u = Y[idx];
        float x[4] = { bf2f((unsigned short)(u.x & 0xffff)), bf2f((unsigned short)(u.x >> 16)),
                       bf2f((unsigned short)(u.y & 0xffff)), bf2f((unsigned short)(u.y >> 16)) };
        #pragma unroll
        for (int e = 0; e < 4; ++e) {
            v[e] = v[e] + 0.1f * ((0.0f - v[e]) + c[e]);
            c[e] = c[e] - 0.2f * c[e] + x[e];
        }
        u.x = (unsigned)f2bf(v[0]) | ((unsigned)f2bf(v[1]) << 16);
        u.y = (unsigned)f2bf(v[2]) | ((unsigned)f2bf(v[3]) << 16);
        Y[idx] = u;
    }
}

// ---- 1x1 heads, 2 pixels/thread
__global__ __launch_bounds__(256) void heads_k(
    const unsigned int* __restrict__ V,
    const float* __restrict__ bw, const float* __restrict__ bb,
    const float* __restrict__ cw, const float* __restrict__ cb,
    float* __restrict__ out)
{
    const int n = blockIdx.x * 256 + threadIdx.x;
    const int tb  = n / (HWD / 2);
    const int hw2 = n - tb * (HWD / 2);
    const unsigned int* vp = V + (size_t)tb * CIN * (HWD / 2) + hw2;

    float b0[12], b1[12], cl0[9], cl1[9];
    #pragma unroll
    for (int o = 0; o < 12; ++o) { b0[o] = bb[o]; b1[o] = bb[o]; }
    #pragma unroll
    for (int o = 0; o < 9;  ++o) { cl0[o] = cb[o]; cl1[o] = cb[o]; }

    for (int ci = 0; ci < CIN; ++ci) {
        const unsigned u = vp[(size_t)ci * (HWD / 2)];
        const float lo = bf2f((unsigned short)(u & 0xffff));
        const float hi = bf2f((unsigned short)(u >> 16));
        #pragma unroll
        for (int o = 0; o < 12; ++o) {
            const float w = bw[o * CIN + ci];
            b0[o] += lo * w; b1[o] += hi * w;
        }
        #pragma unroll
        for (int o = 0; o < 9; ++o) {
            const float w = cw[o * CIN + ci];
            cl0[o] += lo * w; cl1[o] += hi * w;
        }
    }

    const int hw = hw2 * 2;
    float* ob = out + (size_t)tb * 12 * HWD + hw;
    #pragma unroll
    for (int o = 0; o < 12; ++o) { ob[(size_t)o * HWD] = b0[o]; ob[(size_t)o * HWD + 1] = b1[o]; }
    float* oc = out + (size_t)12 * NTB * HWD + (size_t)tb * 9 * HWD + hw;
    #pragma unroll
    for (int o = 0; o < 9;  ++o) { oc[(size_t)o * HWD] = cl0[o]; oc[(size_t)o * HWD + 1] = cl1[o]; }
}

extern "C" void kernel_launch(void* const* d_in, const int* in_sizes, int n_in,
                              void* d_out, int out_size, void* d_ws, size_t ws_size,
                              hipStream_t stream)
{
    const float* X   = (const float*)d_in[0];  // (16,4,256,48,48)
    const float* cw3 = (const float*)d_in[1];  // (256,256,3,3)
    const float* cb3 = (const float*)d_in[2];  // (256,)
    const float* bw  = (const float*)d_in[3];
    const float* bb  = (const float*)d_in[4];
    const float* clw = (const float*)d_in[5];
    const float* clb = (const float*)d_in[6];
    float* out = (float*)d_out;

    unsigned short* Xtp = (unsigned short*)((char*)d_ws + WS_XT);
    unsigned short* At  = (unsigned short*)((char*)d_ws + WS_AT);
    unsigned short* Y   = (unsigned short*)((char*)d_ws + WS_Y);

    hipMemsetAsync(Xtp, 0, 40960000, stream);   // halo zeros (covers both halves)
    prep_w_k<<<288, 256, 0, stream>>>(cw3, At);

    for (int half = 0; half < 2; ++half) {
        const float* Xh = X + (size_t)half * 32 * CIN * HWD;
        prep_x_k<<<dim3(36, 4, 32), 256, 0, stream>>>(Xh, Xtp);
        conv12_k<<<768, 256, 0, stream>>>(Xtp, At, cb3, Y, half * 32);
    }

    li_scan_k<<<SLICE / 1024, 256, 0, stream>>>((uint2*)Y);
    heads_k  <<<NTB * HWD / 512, 256, 0, stream>>>((const unsigned int*)Y,
                                                   bw, bb, clw, clb, out);
}

// Round 12
// 344.594 us; speedup vs baseline: 2.6747x; 2.6747x over previous
//
#include <hip/hip_runtime.h>

#define CIN    256
#define WID    48
#define HWD    2304            // 48*48
#define PHW    2500            // 50*50 padded
#define NTB    64              // ts(16) * b(4)
#define SLICE  (4*CIN*HWD)

// workspace (bytes); ws >= 150,994,944 known-safe
#define WS_XT  0               // Xtp half: 32*4*2500*64*2 = 40,960,000
#define WS_AT  40960000        // A-tiles : 2*36*8192*2   =  1,179,648
#define WS_Y   42139648        // Y bf16  : 64*256*2304*2 = 75,497,472 (ends 117,637,120)

typedef __attribute__((ext_vector_type(8))) short short8v;  // 8 bf16
typedef __attribute__((ext_vector_type(4))) float f32x4;

__device__ __forceinline__ unsigned short f2bf(float f) {
    unsigned u = __float_as_uint(f);
    u = (u + 0x7fffu + ((u >> 16) & 1u)) >> 16;   // RNE
    return (unsigned short)u;
}
__device__ __forceinline__ float bf2f(unsigned short s) {
    return __uint_as_float(((unsigned)s) << 16);
}
__device__ __forceinline__ void gload_lds16(const void* g, void* l) {
    __builtin_amdgcn_global_load_lds(
        (const __attribute__((address_space(1))) unsigned int*)g,
        (__attribute__((address_space(3))) unsigned int*)l, 16, 0, 0);
}

// ---- prep_w: W fp32 -> At bf16, pre-swizzled LDS image, tile order kt2 = g*9 + tap
// At[by][kt2][row(128)][128B]; LDS cell (row,colb) = W[by*128+row][g*64 + (colb^((row&7)<<4))/2] at tap
__global__ __launch_bounds__(256) void prep_w_k(const float* __restrict__ Wt,
                                                unsigned short* __restrict__ At)
{
    const int s = (blockIdx.x * 256 + threadIdx.x) * 8;   // short index < 589824
    const int tile = s >> 13;                 // by*36 + kt2
    const int row  = (s & 8191) >> 6;
    const int colb = (s & 63) * 2;            // byte col (16B-aligned)
    const int by = tile / 36, kt2 = tile - by * 36;
    const int g = kt2 / 9, tap = kt2 - g * 9;
    const int k0 = (colb ^ ((row & 7) << 4)) >> 1;   // elem 0..63, 8-aligned
    const int co = by * 128 + row;
    const float* wp = Wt + (size_t)co * 2304 + (g * 64 + k0) * 9 + tap;
    short8v v;
    #pragma unroll
    for (int j = 0; j < 8; ++j) v[j] = (short)f2bf(wp[j * 9]);
    *(short8v*)(At + s) = v;
}

// ---- prep_x: X fp32 [32tb][ci][px] -> Xtp bf16 [32tb][g][pp(2500)][64ci], halo stays zero
__global__ __launch_bounds__(256) void prep_x_k(const float* __restrict__ X,
                                                unsigned short* __restrict__ Xtp)
{
    __shared__ unsigned short t_[64][72];
    const int tid = threadIdx.x;
    const int px0 = blockIdx.x * 64;
    const int g   = blockIdx.y;               // ci group of 64
    const int tb  = blockIdx.z;

    const int ci_l = tid >> 2, pg = (tid & 3) * 16;
    const float* xp = X + ((size_t)tb * CIN + g * 64 + ci_l) * HWD + px0 + pg;
    #pragma unroll
    for (int q = 0; q < 4; ++q) {
        f32x4 v = *(const f32x4*)(xp + q * 4);
        #pragma unroll
        for (int e = 0; e < 4; ++e)
            t_[pg + q * 4 + e][ci_l] = f2bf(v[e]);
    }
    __syncthreads();
    const int px_l = tid >> 2, cg = (tid & 3) * 16;
    const int p  = px0 + px_l;
    const int pp = p + (p / WID) * 2 + 51;    // (h+1)*50 + (w+1)
    unsigned short* op = Xtp + (((size_t)tb * 4 + g) * PHW + pp) * 64 + cg;
    *(short8v*)op       = *(const short8v*)&t_[px_l][cg];
    *(short8v*)(op + 8) = *(const short8v*)&t_[px_l][cg + 8];
}

// ---- conv (round-6 proven): BM=128 BN=192; B slab staged once per ci-group,
// 9 taps from LDS; per-tap staging = 4 A-loads (L2-resident weights) only
__global__ __launch_bounds__(256, 2) void conv8_k(
    const unsigned short* __restrict__ Xtp, const unsigned short* __restrict__ At,
    const float* __restrict__ Bs, unsigned short* __restrict__ Y, int tb_base)
{
    __shared__ short ldsA[2][8192];    // 128 rows x 128B, double-buffered (32 KB)
    __shared__ short ldsB[19200];      // slab: 300 padded px x 128B (37.5 KB)

    const int tid = threadIdx.x;
    const int wv  = tid >> 6, ln = tid & 63;
    const int lr  = ln & 15,  lg = ln >> 4;
    const int wm  = wv >> 1,  wn = wv & 1;

    // bijective XCD swizzle, nwg=768 (q=96)
    const int orig = blockIdx.x;
    const int wg   = (orig & 7) * 96 + (orig >> 3);
    const int tb_l = wg / 24;
    const int rem  = wg - tb_l * 24;
    const int rt   = rem >> 1;           // row-tile 0..11 (4 image rows)
    const int by   = rem & 1;

    // B-fragment slab-relative pixel offsets (fixed per thread)
    int boff[6];
    #pragma unroll
    for (int ni = 0; ni < 6; ++ni) {
        const int p = wn * 96 + ni * 16 + lr;
        const int r = p / 48, c = p - r * 48;
        boff[ni] = (r + 1) * 50 + (c + 1);
    }

    // A ds_read swizzled column offsets (shorts)
    const int cx0 = ((lg << 4) ^ ((lr & 7) << 4)) >> 1;
    const int cx1 = ((64 | (lg << 4)) ^ ((lr & 7) << 4)) >> 1;

    const unsigned short* Asrc  = At + (size_t)by * 36 * 8192 + wv * 2048 + ln * 8;
    const unsigned short* slab0 = Xtp + (size_t)tb_l * 4 * PHW * 64 + (size_t)rt * 200 * 64;

    f32x4 acc[4][6];
    const f32x4 zero = {0.f, 0.f, 0.f, 0.f};
    #pragma unroll
    for (int i = 0; i < 4; ++i)
        #pragma unroll
        for (int j = 0; j < 6; ++j) acc[i][j] = zero;

    for (int g = 0; g < 4; ++g) {
        // ---- stage B slab (once per ci-group): 2400 16B cells, pre-swizzled source
        const unsigned short* sg = slab0 + (size_t)g * PHW * 64;
        #pragma unroll
        for (int j = 0; j < 10; ++j) {
            const int cc = tid + 256 * j;
            if (cc < 2400) {
                const int p = cc >> 3, k = cc & 7;
                gload_lds16(sg + p * 64 + ((k ^ (p & 7)) << 3),
                            &ldsB[(wv * 64 + 256 * j) * 8]);
            }
        }
        // ---- stage A tile (g, tap0) into buf 0
        const unsigned short* ag = Asrc + (size_t)g * 9 * 8192;
        #pragma unroll
        for (int i = 0; i < 4; ++i)
            gload_lds16(ag + i * 512, &ldsA[0][wv * 2048 + i * 512]);
        asm volatile("s_waitcnt vmcnt(0)" ::: "memory");
        __builtin_amdgcn_sched_barrier(0);
        __builtin_amdgcn_s_barrier();

        #pragma unroll
        for (int tap = 0; tap < 9; ++tap) {
            const int cur = tap & 1;
            if (tap < 8) {                      // prefetch next A tile
                const unsigned short* an = ag + (size_t)(tap + 1) * 8192;
                #pragma unroll
                for (int i = 0; i < 4; ++i)
                    gload_lds16(an + i * 512, &ldsA[cur ^ 1][wv * 2048 + i * 512]);
            }
            const int toff = (tap / 3 - 1) * 50 + (tap % 3 - 1);
            #pragma unroll
            for (int kh = 0; kh < 2; ++kh) {
                const int cx = kh ? cx1 : cx0;
                short8v a_[4], b_[6];
                #pragma unroll
                for (int mi = 0; mi < 4; ++mi)
                    a_[mi] = *(const short8v*)&ldsA[cur][(wm * 64 + mi * 16 + lr) * 64 + cx];
                #pragma unroll
                for (int ni = 0; ni < 6; ++ni) {
                    const int sp = boff[ni] + toff;
                    b_[ni] = *(const short8v*)&ldsB[sp * 64 + ((((kh << 2) | lg) ^ (sp & 7)) << 3)];
                }
                __builtin_amdgcn_s_setprio(1);
                #pragma unroll
                for (int mi = 0; mi < 4; ++mi)
                    #pragma unroll
                    for (int ni = 0; ni < 6; ++ni)
                        acc[mi][ni] = __builtin_amdgcn_mfma_f32_16x16x32_bf16(
                            a_[mi], b_[ni], acc[mi][ni], 0, 0, 0);
                __builtin_amdgcn_s_setprio(0);
            }
            asm volatile("s_waitcnt vmcnt(0)" ::: "memory");   // A(tap+1): 4 loads, L2-warm
            __builtin_amdgcn_sched_barrier(0);
            __builtin_amdgcn_s_barrier();
        }
    }

    // epilogue: D row=(lane>>4)*4+r (m), col=lane&15 (px)
    const int tbg   = tb_base + tb_l;
    const int nbase = rt * 192 + wn * 96;
    #pragma unroll
    for (int mi = 0; mi < 4; ++mi) {
        const int m = by * 128 + wm * 64 + mi * 16 + lg * 4;
        const f32x4 b4 = *(const f32x4*)&Bs[m];
        #pragma unroll
        for (int r = 0; r < 4; ++r) {
            unsigned short* yp = Y + ((size_t)tbg * CIN + m + r) * HWD + nbase;
            #pragma unroll
            for (int ni = 0; ni < 6; ++ni)
                yp[ni * 16 + lr] = f2bf(acc[mi][ni][r] + b4[r]);
        }
    }
}

// ---- LI scan in place on bf16 Y, 8 elems/thread (uint4, 16B/lane)
__global__ __launch_bounds__(256) void li_scan4_k(uint4* __restrict__ Y)
{
    const int n = blockIdx.x * 256 + threadIdx.x;   // uint4 index within slice
    float v[8], c[8];
    #pragma unroll
    for (int e = 0; e < 8; ++e) { v[e] = 0.f; c[e] = 0.f; }
    #pragma unroll
    for (int t = 0; t < 16; ++t) {
        const size_t idx = (size_t)t * (SLICE / 8) + n;
        uint4 u = Y[idx];
        float x[8] = { bf2f((unsigned short)(u.x & 0xffff)), bf2f((unsigned short)(u.x >> 16)),
                       bf2f((unsigned short)(u.y & 0xffff)), bf2f((unsigned short)(u.y >> 16)),
                       bf2f((unsigned short)(u.z & 0xffff)), bf2f((unsigned short)(u.z >> 16)),
                       bf2f((unsigned short)(u.w & 0xffff)), bf2f((unsigned short)(u.w >> 16)) };
        #pragma unroll
        for (int e = 0; e < 8; ++e) {
            v[e] = v[e] + 0.1f * ((0.0f - v[e]) + c[e]);
            c[e] = c[e] - 0.2f * c[e] + x[e];
        }
        u.x = (unsigned)f2bf(v[0]) | ((unsigned)f2bf(v[1]) << 16);
        u.y = (unsigned)f2bf(v[2]) | ((unsigned)f2bf(v[3]) << 16);
        u.z = (unsigned)f2bf(v[4]) | ((unsigned)f2bf(v[5]) << 16);
        u.w = (unsigned)f2bf(v[6]) | ((unsigned)f2bf(v[7]) << 16);
        Y[idx] = u;
    }
}

// ---- 1x1 heads, 2 pixels/thread
__global__ __launch_bounds__(256) void heads_k(
    const unsigned int* __restrict__ V,
    const float* __restrict__ bw, const float* __restrict__ bb,
    const float* __restrict__ cw, const float* __restrict__ cb,
    float* __restrict__ out)
{
    const int n = blockIdx.x * 256 + threadIdx.x;
    const int tb  = n / (HWD / 2);
    const int hw2 = n - tb * (HWD / 2);
    const unsigned int* vp = V + (size_t)tb * CIN * (HWD / 2) + hw2;

    float b0[12], b1[12], cl0[9], cl1[9];
    #pragma unroll
    for (int o = 0; o < 12; ++o) { b0[o] = bb[o]; b1[o] = bb[o]; }
    #pragma unroll
    for (int o = 0; o < 9;  ++o) { cl0[o] = cb[o]; cl1[o] = cb[o]; }

    for (int ci = 0; ci < CIN; ++ci) {
        const unsigned u = vp[(size_t)ci * (HWD / 2)];
        const float lo = bf2f((unsigned short)(u & 0xffff));
        const float hi = bf2f((unsigned short)(u >> 16));
        #pragma unroll
        for (int o = 0; o < 12; ++o) {
            const float w = bw[o * CIN + ci];
            b0[o] += lo * w; b1[o] += hi * w;
        }
        #pragma unroll
        for (int o = 0; o < 9; ++o) {
            const float w = cw[o * CIN + ci];
            cl0[o] += lo * w; cl1[o] += hi * w;
        }
    }

    const int hw = hw2 * 2;
    float* ob = out + (size_t)tb * 12 * HWD + hw;
    #pragma unroll
    for (int o = 0; o < 12; ++o) { ob[(size_t)o * HWD] = b0[o]; ob[(size_t)o * HWD + 1] = b1[o]; }
    float* oc = out + (size_t)12 * NTB * HWD + (size_t)tb * 9 * HWD + hw;
    #pragma unroll
    for (int o = 0; o < 9;  ++o) { oc[(size_t)o * HWD] = cl0[o]; oc[(size_t)o * HWD + 1] = cl1[o]; }
}

extern "C" void kernel_launch(void* const* d_in, const int* in_sizes, int n_in,
                              void* d_out, int out_size, void* d_ws, size_t ws_size,
                              hipStream_t stream)
{
    const float* X   = (const float*)d_in[0];  // (16,4,256,48,48)
    const float* cw3 = (const float*)d_in[1];  // (256,256,3,3)
    const float* cb3 = (const float*)d_in[2];  // (256,)
    const float* bw  = (const float*)d_in[3];
    const float* bb  = (const float*)d_in[4];
    const float* clw = (const float*)d_in[5];
    const float* clb = (const float*)d_in[6];
    float* out = (float*)d_out;

    unsigned short* Xtp = (unsigned short*)((char*)d_ws + WS_XT);
    unsigned short* At  = (unsigned short*)((char*)d_ws + WS_AT);
    unsigned short* Y   = (unsigned short*)((char*)d_ws + WS_Y);

    hipMemsetAsync(Xtp, 0, 40960000, stream);   // halo zeros (covers both halves)
    prep_w_k<<<288, 256, 0, stream>>>(cw3, At);

    for (int half = 0; half < 2; ++half) {
        const float* Xh = X + (size_t)half * 32 * CIN * HWD;
        prep_x_k<<<dim3(36, 4, 32), 256, 0, stream>>>(Xh, Xtp);
        conv8_k<<<768, 256, 0, stream>>>(Xtp, At, cb3, Y, half * 32);
    }

    li_scan4_k<<<SLICE / 2048, 256, 0, stream>>>((uint4*)Y);
    heads_k   <<<NTB * HWD / 512, 256, 0, stream>>>((const unsigned int*)Y,
                                                    bw, bb, clw, clb, out);
}